// Round 8
// baseline (71.712 us; speedup 1.0000x reference)
//
#include <hip/hip_runtime.h>

// MultiScaleGraphConstruction: out[s,b,i,j] = dist(b,i,j) if MIN_DIST < dist < r_s else 0
//
// R8: R7 (plain stores, one plane per blockIdx.z) + block coarsening that
// PRESERVES the write span: 1024-thread blocks own 2 consecutive rows of one
// plane; each thread computes 4 distances and issues exactly ONE dwordx4
// store (no inner loop). Halves block count, cuts per-byte instruction
// overhead ~1/3. Occupancy unchanged: 2 blocks/CU = 32 waves/CU.
//
// Mask equivalence (bit-exact vs reference f32 arithmetic):
//   ref: dist = sqrt_rn(max(sq,1e-12)); mask = (dist < r) & (dist > 1e-6)
//   sqrt_rn monotone + correctly rounded =>
//     dist < 3  <=>  sq < 9.0f
//     dist < 5  <=>  sq < nextbelow(25)  (sqrt_rn(nextbelow(25)) == 5 exactly)
//     dist < 8  <=>  sq < 64.0f
//   dist > 1e-6 <=> sq > 0. Value via v_sqrt_f32 (<=1 ulp << 0.16 threshold).
// sq computed in reference order, no FMA contraction.

namespace {
constexpr int B = 8;
constexpr int N = 2048;                       // pos is (B, N, 3) f32
constexpr long long NN  = (long long)N * N;   // 4,194,304
constexpr long long BNN = (long long)B * NN;  // 33,554,432
typedef float vf4 __attribute__((ext_vector_type(4)));
}

__global__ __launch_bounds__(1024) void msgc_kernel(const float* __restrict__ pos,
                                                    float* __restrict__ out) {
    const int tid = (int)threadIdx.x;
    const int rpair = blockIdx.x;             // 2-row group within (b-major) rows
    const int row0  = rpair << 1;             // global row = b*N + i
    const int b     = row0 >> 11;
    const int i     = (row0 & (N - 1)) + (tid >> 9);   // wave-uniform half select
    const int s     = blockIdx.z;             // scale plane 0..2

    // squared-distance cutoff, bit-exact equivalent of (sqrt_rn(sq) < r)
    const float thr = (s == 0) ? 9.0f
                    : (s == 1) ? __uint_as_float(0x41C7FFFFu)   // nextbelow(25.0f)
                               : 64.0f;

    const float* __restrict__ pb = pos + (size_t)b * N * 3;
    const float xi = pb[3 * i + 0];           // wave-uniform -> scalar loads
    const float yi = pb[3 * i + 1];
    const float zi = pb[3 * i + 2];

    float* __restrict__ orow = out + (size_t)s * BNN + (size_t)b * NN + (size_t)i * N;

    const int j0 = (tid & 511) << 2;          // 4 consecutive j per thread
    const vf4* p4 = reinterpret_cast<const vf4*>(pb + (size_t)j0 * 3);
    const vf4 a = p4[0];
    const vf4 c = p4[1];
    const vf4 e = p4[2];

    const float jx[4] = {a.x, a.w, c.z, e.y};
    const float jy[4] = {a.y, c.x, c.w, e.z};
    const float jz[4] = {a.z, c.y, e.x, e.w};

    vf4 r;
#pragma unroll
    for (int k = 0; k < 4; ++k) {
        const float dx = xi - jx[k];
        const float dy = yi - jy[k];
        const float dz = zi - jz[k];
        // No FMA contraction; reference summation order.
        const float s0 = __fmul_rn(dx, dx);
        const float s1 = __fmul_rn(dy, dy);
        const float s2 = __fmul_rn(dz, dz);
        const float sq = __fadd_rn(__fadd_rn(s0, s1), s2);
        const float dist = __builtin_amdgcn_sqrtf(sq);  // value-only
        r[k] = ((sq > 0.0f) && (sq < thr)) ? dist : 0.0f;
    }

    *reinterpret_cast<vf4*>(orow + j0) = r;   // plain store (L2 writeback aggregation)
}

extern "C" void kernel_launch(void* const* d_in, const int* in_sizes, int n_in,
                              void* d_out, int out_size, void* d_ws, size_t ws_size,
                              hipStream_t stream) {
    const float* pos = (const float*)d_in[0];
    float* out = (float*)d_out;
    msgc_kernel<<<dim3((B * N) / 2, 1, 3), dim3(1024), 0, stream>>>(pos, out);
}

// Round 9
// 64.965 us; speedup vs baseline: 1.1039x; 1.1039x over previous
//
#include <hip/hip_runtime.h>

// MultiScaleGraphConstruction: out[s,b,i,j] = dist(b,i,j) if MIN_DIST < dist < r_s else 0
//
// R9: R7 regime (one 8KB row per block, plain stores, one plane per
// blockIdx.z) with 512-thread blocks: each thread = exactly one float4
// (4 j's) -> one dwordx4 store, no inner loop. Halves per-row dynamic
// instructions vs R7 while keeping the small-block scheduling regime that
// R8 (1024-thr, 2 rows) broke. 8 waves/block, 4 blocks/CU = 32 waves.
//
// Mask equivalence (bit-exact vs reference f32 arithmetic):
//   ref: dist = sqrt_rn(max(sq,1e-12)); mask = (dist < r) & (dist > 1e-6)
//   sqrt_rn monotone + correctly rounded =>
//     dist < 3  <=>  sq < 9.0f
//     dist < 5  <=>  sq < nextbelow(25)  (sqrt_rn(nextbelow(25)) == 5 exactly)
//     dist < 8  <=>  sq < 64.0f
//   dist > 1e-6 <=> sq > 0. Value via v_sqrt_f32 (<=1 ulp << 0.16 threshold).
// sq computed in reference order, no FMA contraction.

namespace {
constexpr int B = 8;
constexpr int N = 2048;                       // pos is (B, N, 3) f32
constexpr long long NN  = (long long)N * N;   // 4,194,304
constexpr long long BNN = (long long)B * NN;  // 33,554,432
typedef float vf4 __attribute__((ext_vector_type(4)));
}

__global__ __launch_bounds__(512) void msgc_kernel(const float* __restrict__ pos,
                                                   float* __restrict__ out) {
    const int bi = blockIdx.x;            // one block per output row (b,i)
    const int b  = bi >> 11;
    const int i  = bi & (N - 1);
    const int s  = blockIdx.z;            // scale plane 0..2

    // squared-distance cutoff, bit-exact equivalent of (sqrt_rn(sq) < r)
    const float thr = (s == 0) ? 9.0f
                    : (s == 1) ? __uint_as_float(0x41C7FFFFu)   // nextbelow(25.0f)
                               : 64.0f;

    const float* __restrict__ pb = pos + (size_t)b * N * 3;
    const float xi = pb[3 * i + 0];       // block-uniform -> scalar loads
    const float yi = pb[3 * i + 1];
    const float zi = pb[3 * i + 2];

    float* __restrict__ orow = out + (size_t)s * BNN + (size_t)b * NN + (size_t)i * N;

    const int j0 = ((int)threadIdx.x) << 2;   // 4 consecutive j per thread
    const vf4* p4 = reinterpret_cast<const vf4*>(pb + (size_t)j0 * 3);
    const vf4 a = p4[0];
    const vf4 c = p4[1];
    const vf4 e = p4[2];

    const float jx[4] = {a.x, a.w, c.z, e.y};
    const float jy[4] = {a.y, c.x, c.w, e.z};
    const float jz[4] = {a.z, c.y, e.x, e.w};

    vf4 r;
#pragma unroll
    for (int k = 0; k < 4; ++k) {
        const float dx = xi - jx[k];
        const float dy = yi - jy[k];
        const float dz = zi - jz[k];
        // No FMA contraction; reference summation order.
        const float s0 = __fmul_rn(dx, dx);
        const float s1 = __fmul_rn(dy, dy);
        const float s2 = __fmul_rn(dz, dz);
        const float sq = __fadd_rn(__fadd_rn(s0, s1), s2);
        const float dist = __builtin_amdgcn_sqrtf(sq);  // value-only
        r[k] = ((sq > 0.0f) && (sq < thr)) ? dist : 0.0f;
    }

    *reinterpret_cast<vf4*>(orow + j0) = r;   // plain store (L2 writeback aggregation)
}

extern "C" void kernel_launch(void* const* d_in, const int* in_sizes, int n_in,
                              void* d_out, int out_size, void* d_ws, size_t ws_size,
                              hipStream_t stream) {
    const float* pos = (const float*)d_in[0];
    float* out = (float*)d_out;
    msgc_kernel<<<dim3(B * N, 1, 3), dim3(512), 0, stream>>>(pos, out);
}